// Round 6
// baseline (131.113 us; speedup 1.0000x reference)
//
#include <hip/hip_runtime.h>
#include <math.h>

typedef _Float16 f16;
typedef _Float16 f16x4 __attribute__((ext_vector_type(4)));
typedef _Float16 f16x8 __attribute__((ext_vector_type(8)));
typedef __bf16 bf16x4 __attribute__((ext_vector_type(4)));
typedef short s16x4 __attribute__((ext_vector_type(4)));
typedef float f32x4 __attribute__((ext_vector_type(4)));
typedef unsigned int u32;

#define MFMA_F16(a, b, c)  __builtin_amdgcn_mfma_f32_16x16x32_f16(a, b, c, 0, 0, 0)
#define MFMA_BF16_K16(a, b, c) __builtin_amdgcn_mfma_f32_16x16x16bf16_1k(a, b, c, 0, 0, 0)

static __device__ inline f16x8 cvt8(const float* p) {
    const float4* p4 = (const float4*)p;
    float4 u0 = p4[0], u1 = p4[1];
    f16x8 r;
    r[0] = (f16)u0.x; r[1] = (f16)u0.y; r[2] = (f16)u0.z; r[3] = (f16)u0.w;
    r[4] = (f16)u1.x; r[5] = (f16)u1.y; r[6] = (f16)u1.z; r[7] = (f16)u1.w;
    return r;
}

static __device__ inline u32 alignsel(u32 hi, u32 lo, u32 sh) {
    return sh ? (u32)(((((unsigned long long)hi) << 32) | lo) >> sh) : lo;
}

// ---------------------------------------------------------------------------
// R6: single fused kernel. Block = (b, x, y-octet), 8 waves, 512 threads.
// Phase A (producer, wave = group g): load x-window [32ic(g)][7r][16c] as 56
//   independent scalar loads/lane -> 7 B-fragments; 36 MFMAs compute
//   K(+bk+rel_h), V(+bv), Q(+bq) for this block's attention window, stored
//   into LDS in R5's exact verified geometry. No workspace, no produce pass.
// Phase B (attention, wave = position y0+wvi): R5's verified loop verbatim
//   (same strides 40/20, bases gpr*105*40 / gpv*4480, steps 600/640).
// LDS: Klds 67.2KB + Vlds 71.7KB + Qlds 16KB + TrwL 4KB = 155.6KB -> 1 blk/CU.
// Window geometry: pos = rr*16+cc; input row = x-3+rr, col = y0-3+cc
//   (zero outside image -> conv = bias, matching reference zero-pad).
//   K tile at wpl=cc (cc<15), V tile at elem cc_v=cc (wp = y0+cc_v).
// ---------------------------------------------------------------------------
__global__ __launch_bounds__(512, 1) void fused_kernel(
    const float* __restrict__ x,
    const float* __restrict__ wq, const float* __restrict__ bq,
    const float* __restrict__ wk, const float* __restrict__ bk,
    const float* __restrict__ wv, const float* __restrict__ bv,
    const float* __restrict__ rel_h, const float* __restrict__ rel_w,
    float* __restrict__ out) {
    __shared__ __align__(16) f16 Klds[33600];     // [g][kh][wpl15][c32] rows 40 f16
    __shared__ __align__(16) __bf16 Vlds[35840];  // [g][kh][c32][e20] rows 20 bf16
    __shared__ __align__(16) f16 Qlds[8192];      // [pos8][1024]
    __shared__ __align__(16) f16 TrwL[2048];      // [g][kw8][c32]

    int bid = blockIdx.x;
    int t = threadIdx.x;
    int G = (bid & 7) * 64 + (bid >> 3);  // XCD swizzle
    int yq = G & 3, xx = (G >> 2) & 31, b = G >> 7;
    int y0 = yq * 8;
    int b8 = b * 8;

    int wvi = t >> 6;
    int lane = t & 63;
    int l15 = lane & 15, quad = lane >> 4, kwl = lane & 7, p8 = (lane >> 3) & 1;
    bool oddq = (quad & 1);

    // ================= Phase A: produce K/V/Q for this block ==============
    {
        int g = wvi;  // wave owns group g

        // ---- x window fragments: 7 rr x 8 ic, 56 independent scalar loads
        const float* xb = x + ((size_t)(b * 256 + g * 32 + quad * 8) * 32) * 32;
        int cX = y0 - 3 + l15;
        bool cok = ((unsigned)cX < 32u);
        f16x8 xf[7];
#pragma unroll
        for (int rr = 0; rr < 7; ++rr) {
            int rX = xx - 3 + rr;
            bool ok = cok && ((unsigned)rX < 32u);
            int off = rX * 32 + cX;
#pragma unroll
            for (int j = 0; j < 8; ++j) {
                float v = ok ? xb[off + j * 1024] : 0.f;
                xf[rr][j] = (f16)v;
            }
        }

        // ---- TrwL staging (read only after the barrier) ----
        for (int i = t; i < 2048; i += 512) {
            int c = i & 31, gw = i >> 5;
            int g2 = gw >> 3, kw = gw & 7;
            TrwL[i] = (f16)((c >= 16 && kw < 7) ? rel_w[(c - 16) * 56 + g2 * 7 + kw] : 0.f);
        }

        // ---- K/V weights + biases ----
        f16x8 wkf[2], wvf[2];
        float4 bk4[2], bv4[2];
#pragma unroll
        for (int ct = 0; ct < 2; ++ct) {
            wkf[ct] = cvt8(wk + ((size_t)g * 32 + ct * 16 + l15) * 32 + quad * 8);
            wvf[ct] = cvt8(wv + ((size_t)g * 32 + ct * 16 + l15) * 32 + quad * 8);
            bk4[ct] = *(const float4*)(bk + g * 32 + ct * 16 + quad * 4);
            bv4[ct] = *(const float4*)(bv + g * 32 + ct * 16 + quad * 4);
        }

        // ---- K and V tiles: per rr, 4 MFMAs; store to Klds/Vlds ----
#pragma unroll
        for (int rr = 0; rr < 7; ++rr) {
            // rel_h for c = quad*4+r (c<16 always when ct==0)
            float rh0 = rel_h[(quad * 4 + 0) * 56 + g * 7 + rr];
            float rh1 = rel_h[(quad * 4 + 1) * 56 + g * 7 + rr];
            float rh2 = rel_h[(quad * 4 + 2) * 56 + g * 7 + rr];
            float rh3 = rel_h[(quad * 4 + 3) * 56 + g * 7 + rr];
#pragma unroll
            for (int ct = 0; ct < 2; ++ct) {
                f32x4 z = {0.f, 0.f, 0.f, 0.f};
                f32x4 dK = MFMA_F16(wkf[ct], xf[rr], z);
                f32x4 dV = MFMA_F16(wvf[ct], xf[rr], z);
                // K store (col l15 = wpl; junk cc=15 dropped)
                f16x4 k4;
                k4[0] = (f16)(dK[0] + bk4[ct].x + (ct ? 0.f : rh0));
                k4[1] = (f16)(dK[1] + bk4[ct].y + (ct ? 0.f : rh1));
                k4[2] = (f16)(dK[2] + bk4[ct].z + (ct ? 0.f : rh2));
                k4[3] = (f16)(dK[3] + bk4[ct].w + (ct ? 0.f : rh3));
                if (l15 < 15)
                    *(f16x4*)(Klds + ((g * 7 + rr) * 15 + l15) * 40 + ct * 16 + quad * 4) = k4;
                // V store (row = c, elem l15 = cc_v)
                int vrow = (g * 7 + rr) * 32 + ct * 16 + quad * 4;
                Vlds[(vrow + 0) * 20 + l15] = (__bf16)(dV[0] + bv4[ct].x);
                Vlds[(vrow + 1) * 20 + l15] = (__bf16)(dV[1] + bv4[ct].y);
                Vlds[(vrow + 2) * 20 + l15] = (__bf16)(dV[2] + bv4[ct].z);
                Vlds[(vrow + 3) * 20 + l15] = (__bf16)(dV[3] + bv4[ct].w);
            }
        }

        // ---- Q: positions y0..y0+7 (= window row rr=3, cols cc=3..10) ----
#pragma unroll
        for (int mq = 0; mq < 8; ++mq) {
            f16x8 wqf = cvt8(wq + ((size_t)g * 128 + mq * 16 + l15) * 32 + quad * 8);
            float4 bq4 = *(const float4*)(bq + g * 128 + mq * 16 + quad * 4);
            f32x4 z = {0.f, 0.f, 0.f, 0.f};
            f32x4 d = MFMA_F16(wqf, xf[3], z);
            if (l15 >= 3 && l15 <= 10) {
                f16x4 q4;
                q4[0] = (f16)(d[0] + bq4.x); q4[1] = (f16)(d[1] + bq4.y);
                q4[2] = (f16)(d[2] + bq4.z); q4[3] = (f16)(d[3] + bq4.w);
                *(f16x4*)(Qlds + (l15 - 3) * 1024 + g * 128 + mq * 16 + quad * 4) = q4;
            }
        }
    }
    __syncthreads();

    // ================= Phase B: attention (R5 verified loop) ==============
    int y = y0 + wvi;

    f16x8 qf[2];
    qf[0] = *(const f16x8*)(Qlds + wvi * 1024 + l15 * 32 + quad * 8);
    qf[1] = *(const f16x8*)(Qlds + wvi * 1024 + 512 + l15 * 32 + quad * 8);

    float fsumT[2] = {0.f, 0.f};
    f32x4 acc[2][2];
#pragma unroll
    for (int ct = 0; ct < 2; ++ct)
#pragma unroll
        for (int m = 0; m < 2; ++m) acc[ct][m] = (f32x4){0.f, 0.f, 0.f, 0.f};

    int wplk = wvi + kwl;                      // <= 14, always in-window
    u32 shsel = (wvi & 1) ? 16u : 0u;
    bool hi4 = (wvi & 2) != 0;
    int eA = ((quad & 1) + (wvi >> 2)) * 4;

#pragma unroll
    for (int chunk = 0; chunk < 4; ++chunk) {
        int gpr = chunk * 2 + p8;
        int gpv = chunk * 2 + (quad >> 1);
        f16x8 rp = *(const f16x8*)(TrwL + (gpr * 8 + kwl) * 32 + quad * 8);
        const f16* kp = Klds + (gpr * 105 + wplk) * 40 + quad * 8;
        const __bf16* vb0 = Vlds + (size_t)gpv * 4480 + l15 * 20 + eA;
        const __bf16* vb1 = vb0 + 320;  // c + 16
#pragma unroll
        for (int kh = 0; kh < 7; ++kh) {
            f16x8 kb = *(const f16x8*)kp;  kp += 600;
            kb += rp;  // K' = K + rel_h(folded) + rel_w
            uint2 A0 = *(const uint2*)vb0;
            uint2 B0 = *(const uint2*)(vb0 + 4);
            uint2 A1 = *(const uint2*)vb1;
            uint2 B1 = *(const uint2*)(vb1 + 4);
            vb0 += 640; vb1 += 640;
            u32 a0 = hi4 ? A0.y : A0.x, a1 = hi4 ? B0.x : A0.y, a2 = hi4 ? B0.y : B0.x;
            s16x4 vf0 = __builtin_bit_cast(s16x4,
                make_uint2(alignsel(a1, a0, shsel), alignsel(a2, a1, shsel)));
            u32 c0 = hi4 ? A1.y : A1.x, c1 = hi4 ? B1.x : A1.y, c2 = hi4 ? B1.y : B1.x;
            s16x4 vf1 = __builtin_bit_cast(s16x4,
                make_uint2(alignsel(c1, c0, shsel), alignsel(c2, c1, shsel)));
#pragma unroll
            for (int Mt = 0; Mt < 2; ++Mt) {
                f32x4 d = {0.f, 0.f, 0.f, 0.f};
                d = MFMA_F16(kb, qf[Mt], d);  // S^T: rows=keys, cols=qi
                float e0 = __expf(d[0]);
                float e1 = __expf(d[1]);
                float e2 = __expf(d[2]);
                float e3 = oddq ? 0.f : __expf(d[3]);  // kw=7 mask
                fsumT[Mt] += (e0 + e1) + (e2 + e3);
                bf16x4 pb;
                pb[0] = (__bf16)e0; pb[1] = (__bf16)e1;
                pb[2] = (__bf16)e2; pb[3] = (__bf16)e3;
                s16x4 pbi = __builtin_bit_cast(s16x4, pb);
                acc[0][Mt] = MFMA_BF16_K16(vf0, pbi, acc[0][Mt]);
                acc[1][Mt] = MFMA_BF16_K16(vf1, pbi, acc[1][Mt]);
            }
        }
    }

    // ---- fsum reduce across quads ----
#pragma unroll
    for (int m = 0; m < 2; ++m) {
        fsumT[m] += __shfl_xor(fsumT[m], 16);
        fsumT[m] += __shfl_xor(fsumT[m], 32);
    }
    float inv[2] = {1.0f / fsumT[0], 1.0f / fsumT[1]};

    // ---- epilogue: normalize, head-sum, write this wave's y ----
#pragma unroll
    for (int Mt = 0; Mt < 2; ++Mt)
#pragma unroll
        for (int ct = 0; ct < 2; ++ct) {
            float v[4];
#pragma unroll
            for (int r = 0; r < 4; ++r) {
                v[r] = acc[ct][Mt][r] * inv[Mt];
                v[r] += __shfl_xor(v[r], 1);
                v[r] += __shfl_xor(v[r], 2);
            }
            if ((l15 & 3) == 0) {
                int g = Mt * 4 + (l15 >> 2);
                float4 o4 = {v[0], v[1], v[2], v[3]};
                *(float4*)(out + ((((size_t)(b8 + g) * 32 + xx) * 32 + y) << 5) +
                           ct * 16 + quad * 4) = o4;
            }
        }
}

// ---------------------------------------------------------------------------
extern "C" void kernel_launch(void* const* d_in, const int* in_sizes, int n_in,
                              void* d_out, int out_size, void* d_ws, size_t ws_size,
                              hipStream_t stream) {
    const float* x     = (const float*)d_in[0];
    const float* wq    = (const float*)d_in[1];
    const float* bq    = (const float*)d_in[2];
    const float* wk    = (const float*)d_in[3];
    const float* bk    = (const float*)d_in[4];
    const float* wv    = (const float*)d_in[5];
    const float* bv    = (const float*)d_in[6];
    const float* rel_h = (const float*)d_in[7];
    const float* rel_w = (const float*)d_in[8];
    float* out = (float*)d_out;
    (void)d_ws; (void)ws_size;  // workspace unused: fully fused

    hipLaunchKernelGGL(fused_kernel, dim3(512), dim3(512), 0, stream,
                       x, wq, bq, wk, bk, wv, bv, rel_h, rel_w, out);
}